// Round 9
// baseline (225.709 us; speedup 1.0000x reference)
//
#include <hip/hip_runtime.h>
#include <hip/hip_bf16.h>
#include <math.h>

#define NN 512
#define CSD 384
#define CZ 128
#define HH 12
#define TMPW 1152          // 192 sq | 192 sk | 192 sv | 144 pq | 144 pk | 288 pv
#define CATH 176
#define CATDIM 2112
#define NSPLIT 6
#define KSPL 352

#define SW 0.14433756729740643f
#define PW 0.13608276348795434f
#define ZW 0.57735026918962576f
#define NEG_INF -3.4028234663852886e38f

typedef float f32x4_t __attribute__((ext_vector_type(4)));
typedef short bf16x8_t __attribute__((ext_vector_type(8)));

union BFU { uint4 q; bf16x8_t v; ushort u[8]; };

static __device__ __forceinline__ ushort f2bf(float f) {
    __hip_bfloat16 h = __float2bfloat16(f);
    return *reinterpret_cast<ushort*>(&h);
}
static __device__ __forceinline__ float bf2f(ushort u) {
    unsigned int v = ((unsigned int)u) << 16;
    return __uint_as_float(v);
}

// ---------------- proj GEMM + fused rotation: tmp[512][1152] = s @ Wcat + bias
__global__ void proj_gemm_kernel(const float* __restrict__ s, const float* __restrict__ rot,
                                 const float* __restrict__ tran,
                                 const float* __restrict__ Wsq, const float* __restrict__ bsq,
                                 const float* __restrict__ Wsk, const float* __restrict__ bsk,
                                 const float* __restrict__ Wsv, const float* __restrict__ bsv,
                                 const float* __restrict__ Wpq, const float* __restrict__ bpq,
                                 const float* __restrict__ Wpk, const float* __restrict__ bpk,
                                 const float* __restrict__ Wpv, const float* __restrict__ bpv,
                                 float* __restrict__ tmp)
{
    int bx = blockIdx.x;            // 24 f-tiles of 48
    int n0 = blockIdx.y * 32;       // 16 n-tiles
    int f0 = bx * 48;
    const float* W; const float* bb; int dout; int segstart;
    if (bx < 4)       { W = Wsq; bb = bsq; dout = 192; segstart = 0; }
    else if (bx < 8)  { W = Wsk; bb = bsk; dout = 192; segstart = 192; }
    else if (bx < 12) { W = Wsv; bb = bsv; dout = 192; segstart = 384; }
    else if (bx < 15) { W = Wpq; bb = bpq; dout = 144; segstart = 576; }
    else if (bx < 18) { W = Wpk; bb = bpk; dout = 144; segstart = 720; }
    else              { W = Wpv; bb = bpv; dout = 288; segstart = 864; }
    int colbase = f0 - segstart;

    __shared__ float St[32][34];
    __shared__ float Ws[32][49];
    int tid = threadIdx.x;
    int ty = tid >> 4, tx = tid & 15;
    float acc[2][3] = {{0,0,0},{0,0,0}};

    for (int k0 = 0; k0 < CSD; k0 += 32) {
        {
            int r = tid >> 3, c4 = (tid & 7) * 4;
            float4 v = *(const float4*)&s[(size_t)(n0 + r) * CSD + k0 + c4];
            St[c4 + 0][r] = v.x; St[c4 + 1][r] = v.y; St[c4 + 2][r] = v.z; St[c4 + 3][r] = v.w;
        }
        for (int e = tid; e < 1536; e += 256) {
            int r = e / 48, c = e % 48;
            Ws[r][c] = W[(size_t)(k0 + r) * dout + colbase + c];
        }
        __syncthreads();
        #pragma unroll
        for (int k = 0; k < 32; k++) {
            float2 a = *(const float2*)&St[k][ty * 2];
            float b0 = Ws[k][tx * 3], b1 = Ws[k][tx * 3 + 1], b2 = Ws[k][tx * 3 + 2];
            acc[0][0] += a.x * b0; acc[0][1] += a.x * b1; acc[0][2] += a.x * b2;
            acc[1][0] += a.y * b0; acc[1][1] += a.y * b1; acc[1][2] += a.y * b2;
        }
        __syncthreads();
    }
    float bv0 = bb[colbase + tx * 3], bv1 = bb[colbase + tx * 3 + 1], bv2 = bb[colbase + tx * 3 + 2];
    #pragma unroll
    for (int r = 0; r < 2; r++) {
        int n = n0 + ty * 2 + r;
        float v0 = acc[r][0] + bv0, v1 = acc[r][1] + bv1, v2 = acc[r][2] + bv2;
        float* o = tmp + (size_t)n * TMPW + f0 + tx * 3;
        if (bx >= 12) {
            const float* R = rot + n * 9;
            const float* T = tran + n * 3;
            float g0 = R[0] * v0 + R[1] * v1 + R[2] * v2 + T[0];
            float g1 = R[3] * v0 + R[4] * v1 + R[5] * v2 + T[1];
            float g2 = R[6] * v0 + R[7] * v1 + R[8] * v2 + T[2];
            o[0] = g0; o[1] = g1; o[2] = g2;
        } else {
            o[0] = v0; o[1] = v1; o[2] = v2;
        }
    }
}

// ---------------- pair-bias + z-transpose: ONE 64-j tile per block, grid (8 jt, 512 i).
// Stage z f32 coalesced->LDS; MFMA (A from LDS, B=Wsb regs) -> sbz;
// transpose LDS columns -> z_t[i][c][j] bf16 global (coalesced 16B stores).
__global__ __launch_bounds__(256) void pairbias_zt_kernel(const float* __restrict__ z,
                                                          const float* __restrict__ Wsb,
                                                          const float* __restrict__ watt,
                                                          float* __restrict__ sbz,
                                                          ushort* __restrict__ z_t)
{
    int jt = blockIdx.x;
    int i  = blockIdx.y;
    int j0 = jt * 64;
    __shared__ float zlin[64 * 132];    // 33.8 KB
    int tid = threadIdx.x;
    int lane = tid & 63, w = tid >> 6;
    int l16 = lane & 15, lhi = lane >> 4;
    float A2 = watt[2] * ZW;

    BFU breg[4];
    #pragma unroll
    for (int kk = 0; kk < 4; kk++) {
        #pragma unroll
        for (int e = 0; e < 8; e++) {
            int k = kk * 32 + lhi * 8 + e;
            float v = (l16 < HH) ? Wsb[k * HH + l16] * A2 : 0.f;
            breg[kk].u[e] = f2bf(v);
        }
    }

    const float* zi = z + (size_t)i * NN * CZ;
    ushort* zti = z_t + (size_t)i * CZ * NN;

    // ---- stage: coalesced float4 -> zlin (pad 132)
    {
        int r8 = tid >> 3, cq = tid & 7;
        #pragma unroll
        for (int p = 0; p < 2; p++) {
            int row = r8 + p * 32;
            const float* src = zi + (size_t)(j0 + row) * CZ;
            #pragma unroll
            for (int q = 0; q < 4; q++) {
                int c4 = (cq + q * 8) * 4;
                *(float4*)&zlin[row * 132 + c4] = *(const float4*)&src[c4];
            }
        }
    }
    __syncthreads();

    // ---- sbz MFMA: wave w owns rows j0 + w*16 + m
    {
        f32x4_t acc = {0.f, 0.f, 0.f, 0.f};
        #pragma unroll
        for (int kk = 0; kk < 4; kk++) {
            int c0 = kk * 32 + lhi * 8;
            float4 f0 = *(const float4*)&zlin[(w * 16 + l16) * 132 + c0];
            float4 f1 = *(const float4*)&zlin[(w * 16 + l16) * 132 + c0 + 4];
            BFU a;
            a.u[0] = f2bf(f0.x); a.u[1] = f2bf(f0.y); a.u[2] = f2bf(f0.z); a.u[3] = f2bf(f0.w);
            a.u[4] = f2bf(f1.x); a.u[5] = f2bf(f1.y); a.u[6] = f2bf(f1.z); a.u[7] = f2bf(f1.w);
            acc = __builtin_amdgcn_mfma_f32_16x16x32_bf16(a.v, breg[kk].v, acc, 0, 0, 0);
        }
        if (l16 < HH) {
            #pragma unroll
            for (int r = 0; r < 4; r++)
                sbz[((size_t)i * NN + j0 + w * 16 + lhi * 4 + r) * HH + l16] = acc[r];
        }
    }

    // ---- transpose out: z_t[c][j0+jg*8 .. +7], staggered column reads
    {
        int cbase = tid >> 3, jg = tid & 7;
        #pragma unroll
        for (int t = 0; t < 4; t++) {
            int c = cbase + t * 32;
            BFU o;
            #pragma unroll
            for (int q = 0; q < 8; q++) {
                int e = (q + jg) & 7;
                o.u[e] = f2bf(zlin[(jg * 8 + e) * 132 + c]);
            }
            *(uint4*)&zti[(size_t)c * NN + j0 + jg * 8] = o.q;
        }
    }
}

// ---------------- fused logits + softmax (no z): block per i; attn written bf16.
__global__ void logits_softmax_kernel(const float* __restrict__ sbz, const float* __restrict__ resm,
                                      const float* __restrict__ bsb,
                                      const float* __restrict__ watt, const float* __restrict__ batt,
                                      const float* __restrict__ tpw, const float* __restrict__ tmp,
                                      ushort* __restrict__ attn_bf)
{
    int i = blockIdx.x;
    __shared__ float lt[NN * 17];       // logits [j][h], pad 17 (34.8 KB)
    __shared__ float sqs[192];
    __shared__ float pqi[144];
    __shared__ float cpt[12];
    __shared__ float cb[12];
    int tid = threadIdx.x;
    float w0 = watt[0], w1 = watt[1], w2 = watt[2], ba = batt[0];
    float A2 = w2 * ZW;

    for (int k = tid; k < 192; k += 256) sqs[k] = tmp[(size_t)i * TMPW + k] * (SW * w0);
    if (tid < 144) pqi[tid] = tmp[(size_t)i * TMPW + 576 + tid];
    if (tid < 12) {
        cpt[tid] = -0.5f * log1pf(expf(tpw[tid])) * PW * w1;
        cb[tid]  = A2 * bsb[tid] + ba;
    }
    __syncthreads();

    int jg = tid >> 2, hg = tid & 3, h0 = hg * 3;
    float rmi = resm[i];
    const float* sbi = sbz + (size_t)i * NN * HH;

    #pragma unroll
    for (int rr = 0; rr < 8; rr++) {
        int j = jg + 64 * rr;
        float mj = rmi * resm[j];
        const float* sbr = &sbi[(size_t)j * HH + h0];
        float pb[3] = { sbr[0], sbr[1], sbr[2] };
        #pragma unroll
        for (int t = 0; t < 3; t++) {
            int h = h0 + t;
            const float4* skp = (const float4*)(tmp + (size_t)j * TMPW + 192 + h * 16);
            const float4* sqp = (const float4*)&sqs[h * 16];
            float d0 = 0.f;
            #pragma unroll
            for (int q = 0; q < 4; q++) {
                float4 kv = skp[q];
                float4 qv = sqp[q];
                d0 += qv.x * kv.x + qv.y * kv.y + qv.z * kv.z + qv.w * kv.w;
            }
            const float4* pkp = (const float4*)(tmp + (size_t)j * TMPW + 720 + h * 12);
            const float4* pqp = (const float4*)&pqi[h * 12];
            float sd = 0.f;
            #pragma unroll
            for (int q = 0; q < 3; q++) {
                float4 kv = pkp[q];
                float4 qv = pqp[q];
                float a = qv.x - kv.x, bb2 = qv.y - kv.y, cc = qv.z - kv.z, e = qv.w - kv.w;
                sd += a * a + bb2 * bb2 + cc * cc + e * e;
            }
            float lg = cb[h] + pb[t] + d0 + cpt[h] * sd;
            if (mj == 0.f) lg = NEG_INF;
            lt[j * 17 + h] = lg;
        }
    }
    __syncthreads();

    int wid = tid >> 6, lane = tid & 63;
    #pragma unroll
    for (int t = 0; t < 3; t++) {
        int h = wid * 3 + t;
        float v[8]; float m = -INFINITY;
        #pragma unroll
        for (int u = 0; u < 8; u++) { v[u] = lt[(lane + 64 * u) * 17 + h]; m = fmaxf(m, v[u]); }
        for (int off = 32; off; off >>= 1) m = fmaxf(m, __shfl_xor(m, off));
        float ssum = 0.f;
        #pragma unroll
        for (int u = 0; u < 8; u++) { v[u] = __expf(v[u] - m); ssum += v[u]; }
        for (int off = 32; off; off >>= 1) ssum += __shfl_xor(ssum, off);
        float inv = 1.f / ssum;
        ushort* ag = attn_bf + ((size_t)i * HH + h) * NN;
        #pragma unroll
        for (int u = 0; u < 8; u++) ag[lane + 64 * u] = f2bf(v[u] * inv);
    }
}

// ---------------- r_pair via MFMA on z_t: D[c][h] = sum_j z_t[c][j] * P[h][j]
__global__ __launch_bounds__(256) void rpair_kernel(const ushort* __restrict__ z_t,
                                                    const ushort* __restrict__ attn_bf,
                                                    float* __restrict__ cat)
{
    int i = blockIdx.x;
    __shared__ uint4 Pl[16 * 64];       // 16 KB
    int tid = threadIdx.x;

    const ushort* ab = attn_bf + (size_t)i * HH * NN;
    #pragma unroll
    for (int u = 0; u < 4; u++) {
        int s2 = tid + 256 * u;
        int m = s2 >> 6, g = s2 & 63;
        uint4 val;
        if (m < HH) val = *(const uint4*)&ab[(size_t)m * NN + g * 8];
        else { val.x = 0; val.y = 0; val.z = 0; val.w = 0; }
        Pl[m * 64 + (g ^ (m & 7))] = val;
    }
    __syncthreads();

    int w = tid >> 6, lane = tid & 63;
    int l16 = lane & 15, lhi = lane >> 4;
    int c0 = w * 32;
    const ushort* zti = z_t + (size_t)i * CZ * NN;
    f32x4_t acc0 = {0.f, 0.f, 0.f, 0.f};
    f32x4_t acc1 = {0.f, 0.f, 0.f, 0.f};

    #pragma unroll 4
    for (int kk = 0; kk < 16; kk++) {
        BFU b; b.q = Pl[l16 * 64 + ((kk * 4 + lhi) ^ (l16 & 7))];
        BFU a0, a1;
        a0.q = *(const uint4*)&zti[(size_t)(c0 + l16) * NN + kk * 32 + lhi * 8];
        a1.q = *(const uint4*)&zti[(size_t)(c0 + 16 + l16) * NN + kk * 32 + lhi * 8];
        acc0 = __builtin_amdgcn_mfma_f32_16x16x32_bf16(a0.v, b.v, acc0, 0, 0, 0);
        acc1 = __builtin_amdgcn_mfma_f32_16x16x32_bf16(a1.v, b.v, acc1, 0, 0, 0);
    }

    // D: col = lane&15 = h, row = lhi*4 + r = c within tile
    if (l16 < HH) {
        float* cp = cat + (size_t)i * CATDIM + l16 * CATH + 48;
        #pragma unroll
        for (int r = 0; r < 4; r++) {
            cp[c0 + lhi * 4 + r]      = acc0[r];
            cp[c0 + 16 + lhi * 4 + r] = acc1[r];
        }
    }
}

// ---------------- per-head r_scalar + r_pt (+rotate back, norm); attn bf16
__global__ void head_sum_kernel(const ushort* __restrict__ attn_bf, const float* __restrict__ tmp,
                                const float* __restrict__ rot, const float* __restrict__ tran,
                                float* __restrict__ cat)
{
    int i0 = blockIdx.x * 32;
    int h  = blockIdx.y;
    __shared__ float At[32][65];
    __shared__ float Sr[64][44];
    __shared__ float Rp[32][24];
    int tid = threadIdx.x;
    int il = tid & 31, fg = tid >> 5;
    float acc[5] = {0,0,0,0,0};

    for (int jc = 0; jc < NN; jc += 64) {
        {
            int r = tid >> 3, c8 = (tid & 7) * 8;
            const ushort* src = attn_bf + ((size_t)(i0 + r) * HH + h) * NN + jc + c8;
            BFU v; v.q = *(const uint4*)src;
            #pragma unroll
            for (int q = 0; q < 8; q++) At[r][c8 + q] = bf2f(v.u[q]);
        }
        {
            int jr = tid >> 2, d4 = (tid & 3) * 4;
            *(float4*)&Sr[jr][d4] = *(const float4*)&tmp[(size_t)(jc + jr) * TMPW + 384 + h * 16 + d4];
        }
        for (int e = tid; e < 384; e += 256) {
            int jr = e / 6, p4 = (e % 6) * 4;
            *(float4*)&Sr[jr][16 + p4] = *(const float4*)&tmp[(size_t)(jc + jr) * TMPW + 864 + h * 24 + p4];
        }
        __syncthreads();
        #pragma unroll 4
        for (int j = 0; j < 64; j++) {
            float a = At[il][j];
            #pragma unroll
            for (int q = 0; q < 5; q++) acc[q] += a * Sr[j][fg * 5 + q];
        }
        __syncthreads();
    }

    float* cbase = cat + (size_t)(i0 + il) * CATDIM + h * CATH;
    #pragma unroll
    for (int q = 0; q < 5; q++) {
        int f = fg * 5 + q;
        if (f < 16) cbase[f] = acc[q];
        else Rp[il][f - 16] = acc[q];
    }
    __syncthreads();

    {
        int il2 = tid >> 3, p = tid & 7;
        int i = i0 + il2;
        float gx = Rp[il2][p * 3 + 0] - tran[i * 3 + 0];
        float gy = Rp[il2][p * 3 + 1] - tran[i * 3 + 1];
        float gz = Rp[il2][p * 3 + 2] - tran[i * 3 + 2];
        const float* R = rot + i * 9;
        float lx = R[0] * gx + R[3] * gy + R[6] * gz;
        float ly = R[1] * gx + R[4] * gy + R[7] * gz;
        float lz = R[2] * gx + R[5] * gy + R[8] * gz;
        float nrm = sqrtf(lx * lx + ly * ly + lz * lz + 1e-8f);
        float* cp = cat + (size_t)i * CATDIM + h * CATH;
        cp[16 + p * 3 + 0] = lx; cp[16 + p * 3 + 1] = ly; cp[16 + p * 3 + 2] = lz;
        cp[40 + p] = nrm;
    }
}

// ---------------- out GEMM, K-split
__global__ void out_gemm_split_kernel(const float* __restrict__ cat, const float* __restrict__ Wout,
                                      float* __restrict__ part)
{
    int n0 = blockIdx.x * 64;
    int i0 = blockIdx.y * 64;
    int ks = blockIdx.z * KSPL;
    __shared__ float St[32][68];
    __shared__ float Bs[32][68];
    int tid = threadIdx.x;
    int ty = tid >> 4, tx = tid & 15;
    float acc[4][4] = {{0,0,0,0},{0,0,0,0},{0,0,0,0},{0,0,0,0}};

    for (int k0 = 0; k0 < KSPL; k0 += 32) {
        {
            int r = tid >> 2, c8 = (tid & 3) * 8;
            const float* src = cat + (size_t)(i0 + r) * CATDIM + ks + k0 + c8;
            float4 v0 = *(const float4*)src;
            float4 v1 = *(const float4*)(src + 4);
            St[c8+0][r]=v0.x; St[c8+1][r]=v0.y; St[c8+2][r]=v0.z; St[c8+3][r]=v0.w;
            St[c8+4][r]=v1.x; St[c8+5][r]=v1.y; St[c8+6][r]=v1.z; St[c8+7][r]=v1.w;
        }
        {
            int r = tid >> 3, c8 = (tid & 7) * 8;
            const float* src = Wout + (size_t)(ks + k0 + r) * CSD + n0 + c8;
            *(float4*)&Bs[r][c8]     = *(const float4*)src;
            *(float4*)&Bs[r][c8 + 4] = *(const float4*)(src + 4);
        }
        __syncthreads();
        #pragma unroll
        for (int k = 0; k < 32; k++) {
            float4 a = *(const float4*)&St[k][ty * 4];
            float4 b = *(const float4*)&Bs[k][tx * 4];
            float av[4] = {a.x, a.y, a.z, a.w};
            float bv[4] = {b.x, b.y, b.z, b.w};
            #pragma unroll
            for (int r = 0; r < 4; r++)
                #pragma unroll
                for (int c = 0; c < 4; c++) acc[r][c] += av[r] * bv[c];
        }
        __syncthreads();
    }
    #pragma unroll
    for (int r = 0; r < 4; r++) {
        float4 v = make_float4(acc[r][0], acc[r][1], acc[r][2], acc[r][3]);
        *(float4*)&part[((size_t)blockIdx.z * NN + i0 + ty * 4 + r) * CSD + n0 + tx * 4] = v;
    }
}

__global__ void reduce_out_kernel(const float* __restrict__ part, const float* __restrict__ bout,
                                  float* __restrict__ out)
{
    int v = blockIdx.x * 256 + threadIdx.x;
    int n4 = v % 96;
    float4 o = ((const float4*)bout)[n4];
    const float4* p4 = (const float4*)part;
    #pragma unroll
    for (int s = 0; s < NSPLIT; s++) {
        float4 t = p4[(size_t)s * 49152 + v];
        o.x += t.x; o.y += t.y; o.z += t.z; o.w += t.w;
    }
    ((float4*)out)[v] = o;
}

extern "C" void kernel_launch(void* const* d_in, const int* in_sizes, int n_in,
                              void* d_out, int out_size, void* d_ws, size_t ws_size,
                              hipStream_t stream) {
    const float* s    = (const float*)d_in[0];
    const float* z    = (const float*)d_in[1];
    const float* rot  = (const float*)d_in[2];
    const float* tran = (const float*)d_in[3];
    const float* resm = (const float*)d_in[4];
    const float* Wsq  = (const float*)d_in[5];  const float* bsq = (const float*)d_in[6];
    const float* Wsk  = (const float*)d_in[7];  const float* bsk = (const float*)d_in[8];
    const float* Wsv  = (const float*)d_in[9];  const float* bsv = (const float*)d_in[10];
    const float* Wsb  = (const float*)d_in[11]; const float* bsb = (const float*)d_in[12];
    const float* Wpq  = (const float*)d_in[13]; const float* bpq = (const float*)d_in[14];
    const float* Wpk  = (const float*)d_in[15]; const float* bpk = (const float*)d_in[16];
    const float* Wpv  = (const float*)d_in[17]; const float* bpv = (const float*)d_in[18];
    const float* watt = (const float*)d_in[19]; const float* batt = (const float*)d_in[20];
    const float* tpw  = (const float*)d_in[21];
    const float* Wout = (const float*)d_in[22]; const float* bout = (const float*)d_in[23];
    float* out = (float*)d_out;
    float* ws  = (float*)d_ws;

    float*  tmp     = ws;                        // 589824 floats
    ushort* attn_bf = (ushort*)(ws + 589824);    // 3145728 ushorts (1572864 f-slots)
    float*  sbz     = ws + 589824 + 1572864;     // 3145728 floats
    ushort* z_t     = (ushort*)(ws + 5308416);   // 512*128*512 ushorts (16777216 f-slots)
    float*  cat     = ws + 22085632;             // 1081344 floats
    float*  partO   = ws + 23166976;             // 1179648 floats

    proj_gemm_kernel<<<dim3(24, 16), 256, 0, stream>>>(s, rot, tran,
                                                       Wsq, bsq, Wsk, bsk, Wsv, bsv,
                                                       Wpq, bpq, Wpk, bpk, Wpv, bpv, tmp);
    pairbias_zt_kernel<<<dim3(8, 512), 256, 0, stream>>>(z, Wsb, watt, sbz, z_t);
    logits_softmax_kernel<<<512, 256, 0, stream>>>(sbz, resm, bsb, watt, batt, tpw,
                                                   tmp, attn_bf);
    rpair_kernel<<<512, 256, 0, stream>>>(z_t, attn_bf, cat);
    head_sum_kernel<<<dim3(16, 12), 256, 0, stream>>>(attn_bf, tmp, rot, tran, cat);
    out_gemm_split_kernel<<<dim3(6, 8, NSPLIT), 256, 0, stream>>>(cat, Wout, partO);
    reduce_out_kernel<<<192, 256, 0, stream>>>(partO, bout, out);
}

// Round 10
// 182.333 us; speedup vs baseline: 1.2379x; 1.2379x over previous
//
#include <hip/hip_runtime.h>
#include <hip/hip_bf16.h>
#include <math.h>

#define NN 512
#define CSD 384
#define CZ 128
#define HH 12
#define TMPW 1152          // 192 sq | 192 sk | 192 sv | 144 pq | 144 pk | 288 pv
#define CATH 176
#define CATDIM 2112
#define NSPLIT 6
#define KSPL 352

#define SW 0.14433756729740643f
#define PW 0.13608276348795434f
#define ZW 0.57735026918962576f
#define NEG_INF -3.4028234663852886e38f

typedef float f32x4_t __attribute__((ext_vector_type(4)));
typedef short bf16x8_t __attribute__((ext_vector_type(8)));

union BFU { uint4 q; bf16x8_t v; ushort u[8]; };

static __device__ __forceinline__ ushort f2bf(float f) {
    __hip_bfloat16 h = __float2bfloat16(f);
    return *reinterpret_cast<ushort*>(&h);
}
static __device__ __forceinline__ float bf2f(ushort u) {
    unsigned int v = ((unsigned int)u) << 16;
    return __uint_as_float(v);
}

// ---------------- proj GEMM + fused rotation: tmp[512][1152] = s @ Wcat + bias
__global__ void proj_gemm_kernel(const float* __restrict__ s, const float* __restrict__ rot,
                                 const float* __restrict__ tran,
                                 const float* __restrict__ Wsq, const float* __restrict__ bsq,
                                 const float* __restrict__ Wsk, const float* __restrict__ bsk,
                                 const float* __restrict__ Wsv, const float* __restrict__ bsv,
                                 const float* __restrict__ Wpq, const float* __restrict__ bpq,
                                 const float* __restrict__ Wpk, const float* __restrict__ bpk,
                                 const float* __restrict__ Wpv, const float* __restrict__ bpv,
                                 float* __restrict__ tmp)
{
    int bx = blockIdx.x;            // 24 f-tiles of 48
    int n0 = blockIdx.y * 32;       // 16 n-tiles
    int f0 = bx * 48;
    const float* W; const float* bb; int dout; int segstart;
    if (bx < 4)       { W = Wsq; bb = bsq; dout = 192; segstart = 0; }
    else if (bx < 8)  { W = Wsk; bb = bsk; dout = 192; segstart = 192; }
    else if (bx < 12) { W = Wsv; bb = bsv; dout = 192; segstart = 384; }
    else if (bx < 15) { W = Wpq; bb = bpq; dout = 144; segstart = 576; }
    else if (bx < 18) { W = Wpk; bb = bpk; dout = 144; segstart = 720; }
    else              { W = Wpv; bb = bpv; dout = 288; segstart = 864; }
    int colbase = f0 - segstart;

    __shared__ float St[32][34];
    __shared__ float Ws[32][49];
    int tid = threadIdx.x;
    int ty = tid >> 4, tx = tid & 15;
    float acc[2][3] = {{0,0,0},{0,0,0}};

    for (int k0 = 0; k0 < CSD; k0 += 32) {
        {
            int r = tid >> 3, c4 = (tid & 7) * 4;
            float4 v = *(const float4*)&s[(size_t)(n0 + r) * CSD + k0 + c4];
            St[c4 + 0][r] = v.x; St[c4 + 1][r] = v.y; St[c4 + 2][r] = v.z; St[c4 + 3][r] = v.w;
        }
        for (int e = tid; e < 1536; e += 256) {
            int r = e / 48, c = e % 48;
            Ws[r][c] = W[(size_t)(k0 + r) * dout + colbase + c];
        }
        __syncthreads();
        #pragma unroll
        for (int k = 0; k < 32; k++) {
            float2 a = *(const float2*)&St[k][ty * 2];
            float b0 = Ws[k][tx * 3], b1 = Ws[k][tx * 3 + 1], b2 = Ws[k][tx * 3 + 2];
            acc[0][0] += a.x * b0; acc[0][1] += a.x * b1; acc[0][2] += a.x * b2;
            acc[1][0] += a.y * b0; acc[1][1] += a.y * b1; acc[1][2] += a.y * b2;
        }
        __syncthreads();
    }
    float bv0 = bb[colbase + tx * 3], bv1 = bb[colbase + tx * 3 + 1], bv2 = bb[colbase + tx * 3 + 2];
    #pragma unroll
    for (int r = 0; r < 2; r++) {
        int n = n0 + ty * 2 + r;
        float v0 = acc[r][0] + bv0, v1 = acc[r][1] + bv1, v2 = acc[r][2] + bv2;
        float* o = tmp + (size_t)n * TMPW + f0 + tx * 3;
        if (bx >= 12) {
            const float* R = rot + n * 9;
            const float* T = tran + n * 3;
            float g0 = R[0] * v0 + R[1] * v1 + R[2] * v2 + T[0];
            float g1 = R[3] * v0 + R[4] * v1 + R[5] * v2 + T[1];
            float g2 = R[6] * v0 + R[7] * v1 + R[8] * v2 + T[2];
            o[0] = g0; o[1] = g1; o[2] = g2;
        } else {
            o[0] = v0; o[1] = v1; o[2] = v2;
        }
    }
}

// ---------------- the full z-path, one block per i, 512 threads (8 waves).
// A: sbz via per-wave MFMA (2-deep pipelined z stream) -> LDS
// B: logits (sbz LDS + L2-hot tmp) -> lt
// C: softmax -> lt (f32) + attn_bf (global bf16)
// D: r_pair pure-VALU streaming (z 2nd read from L3), LDS partial reduce -> cat
__global__ __launch_bounds__(512) void fused_z_kernel(const float* __restrict__ z,
                                                      const float* __restrict__ resm,
                                                      const float* __restrict__ Wsb,
                                                      const float* __restrict__ bsb,
                                                      const float* __restrict__ watt,
                                                      const float* __restrict__ batt,
                                                      const float* __restrict__ tpw,
                                                      const float* __restrict__ tmp,
                                                      ushort* __restrict__ attn_bf,
                                                      float* __restrict__ cat)
{
    int i = blockIdx.x;
    __shared__ float lt[NN * 17];       // 34.8 KB logits/attn [j][h]
    __shared__ float sbz[NN * 12];      // 24.6 KB pair-bias [j][h]; reused as pslab in D
    __shared__ float sqs[192];
    __shared__ float pqi[144];
    __shared__ float cpt[12];
    __shared__ float cb[12];
    int tid = threadIdx.x;
    int w = tid >> 6, lane = tid & 63;
    int l16 = lane & 15, lhi = lane >> 4;
    float w0 = watt[0], w1 = watt[1], w2 = watt[2], ba = batt[0];
    float A2 = w2 * ZW;

    for (int k = tid; k < 192; k += 512) sqs[k] = tmp[(size_t)i * TMPW + k] * (SW * w0);
    if (tid < 144) pqi[tid] = tmp[(size_t)i * TMPW + 576 + tid];
    if (tid < 12) {
        cpt[tid] = -0.5f * log1pf(expf(tpw[tid])) * PW * w1;
        cb[tid]  = A2 * bsb[tid] + ba;
    }

    // B-fragments of scaled Wsb, kept in registers
    BFU breg[4];
    #pragma unroll
    for (int kk = 0; kk < 4; kk++) {
        #pragma unroll
        for (int e = 0; e < 8; e++) {
            int k = kk * 32 + lhi * 8 + e;
            float v = (l16 < HH) ? Wsb[k * HH + l16] * A2 : 0.f;
            breg[kk].u[e] = f2bf(v);
        }
    }

    // ---- phase A: sbz. wave w -> tiles T = w + 8t (16 rows each), 2-deep pipeline
    const float* zi = z + (size_t)i * NN * CZ;
    float4 prA[8], prB[8];
    {
        const float* zr = zi + (size_t)(w * 16 + l16) * CZ + lhi * 8;
        #pragma unroll
        for (int kk = 0; kk < 4; kk++) {
            prA[kk * 2]     = *(const float4*)&zr[kk * 32];
            prA[kk * 2 + 1] = *(const float4*)&zr[kk * 32 + 4];
        }
    }
    #pragma unroll
    for (int t = 0; t < 4; t++) {
        float4* cur = (t & 1) ? prB : prA;
        float4* nxt = (t & 1) ? prA : prB;
        if (t < 3) {
            const float* zr = zi + (size_t)((w + 8 * (t + 1)) * 16 + l16) * CZ + lhi * 8;
            #pragma unroll
            for (int kk = 0; kk < 4; kk++) {
                nxt[kk * 2]     = *(const float4*)&zr[kk * 32];
                nxt[kk * 2 + 1] = *(const float4*)&zr[kk * 32 + 4];
            }
        }
        f32x4_t acc = {0.f, 0.f, 0.f, 0.f};
        #pragma unroll
        for (int kk = 0; kk < 4; kk++) {
            float4 f0 = cur[kk * 2], f1 = cur[kk * 2 + 1];
            BFU a;
            a.u[0] = f2bf(f0.x); a.u[1] = f2bf(f0.y); a.u[2] = f2bf(f0.z); a.u[3] = f2bf(f0.w);
            a.u[4] = f2bf(f1.x); a.u[5] = f2bf(f1.y); a.u[6] = f2bf(f1.z); a.u[7] = f2bf(f1.w);
            acc = __builtin_amdgcn_mfma_f32_16x16x32_bf16(a.v, breg[kk].v, acc, 0, 0, 0);
        }
        if (l16 < HH) {
            int T = w + 8 * t;
            #pragma unroll
            for (int r = 0; r < 4; r++)
                sbz[(T * 16 + lhi * 4 + r) * 12 + l16] = acc[r];
        }
    }
    __syncthreads();

    // ---- phase B: logits into lt[j][h]
    {
        int jg = tid >> 2, hg = tid & 3, h0 = hg * 3;
        float rmi = resm[i];
        #pragma unroll
        for (int rr = 0; rr < 4; rr++) {
            int j = jg + 128 * rr;
            float mj = rmi * resm[j];
            const float* sbr = &sbz[j * 12 + h0];
            #pragma unroll
            for (int t = 0; t < 3; t++) {
                int h = h0 + t;
                const float4* skp = (const float4*)(tmp + (size_t)j * TMPW + 192 + h * 16);
                const float4* sqp = (const float4*)&sqs[h * 16];
                float d0 = 0.f;
                #pragma unroll
                for (int q = 0; q < 4; q++) {
                    float4 kv = skp[q];
                    float4 qv = sqp[q];
                    d0 += qv.x * kv.x + qv.y * kv.y + qv.z * kv.z + qv.w * kv.w;
                }
                const float4* pkp = (const float4*)(tmp + (size_t)j * TMPW + 720 + h * 12);
                const float4* pqp = (const float4*)&pqi[h * 12];
                float sd = 0.f;
                #pragma unroll
                for (int q = 0; q < 3; q++) {
                    float4 kv = pkp[q];
                    float4 qv = pqp[q];
                    float a = qv.x - kv.x, bb2 = qv.y - kv.y, cc = qv.z - kv.z, e = qv.w - kv.w;
                    sd += a * a + bb2 * bb2 + cc * cc + e * e;
                }
                float lg = cb[h] + sbr[t] + d0 + cpt[h] * sd;
                if (mj == 0.f) lg = NEG_INF;
                lt[j * 17 + h] = lg;
            }
        }
    }
    __syncthreads();

    // ---- phase C: softmax (waves 0-3, 3 heads each); write lt f32 + attn_bf bf16
    if (w < 4) {
        #pragma unroll
        for (int t = 0; t < 3; t++) {
            int h = w * 3 + t;
            float v[8]; float m = -INFINITY;
            #pragma unroll
            for (int u = 0; u < 8; u++) { v[u] = lt[(lane + 64 * u) * 17 + h]; m = fmaxf(m, v[u]); }
            for (int off = 32; off; off >>= 1) m = fmaxf(m, __shfl_xor(m, off));
            float ssum = 0.f;
            #pragma unroll
            for (int u = 0; u < 8; u++) { v[u] = __expf(v[u] - m); ssum += v[u]; }
            for (int off = 32; off; off >>= 1) ssum += __shfl_xor(ssum, off);
            float inv = 1.f / ssum;
            ushort* ag = attn_bf + ((size_t)i * HH + h) * NN;
            #pragma unroll
            for (int u = 0; u < 8; u++) {
                float p = v[u] * inv;
                lt[(lane + 64 * u) * 17 + h] = p;
                ag[lane + 64 * u] = f2bf(p);
            }
        }
    }
    __syncthreads();

    // ---- phase D: r_pair f32 streaming. wave w -> j-quarter (w>>1), c-half (w&1).
    {
        int jq = w >> 1;
        int c = (w & 1) * 64 + lane;
        float acc[12];
        #pragma unroll
        for (int h = 0; h < 12; h++) acc[h] = 0.f;
        const float* zq = zi + (size_t)(jq * 128) * CZ + c;
        for (int j = 0; j < 128; j += 8) {
            float zv[8];
            #pragma unroll
            for (int u = 0; u < 8; u++) zv[u] = zq[(size_t)(j + u) * CZ];
            #pragma unroll
            for (int u = 0; u < 8; u++) {
                const float* pr = &lt[(jq * 128 + j + u) * 17];
                #pragma unroll
                for (int h = 0; h < 12; h++) acc[h] += pr[h] * zv[u];
            }
        }
        float* pslab = sbz;     // reuse: [jq][h][c] = 4*12*128
        #pragma unroll
        for (int h = 0; h < 12; h++) pslab[(jq * 12 + h) * 128 + c] = acc[h];
    }
    __syncthreads();

    for (int e = tid; e < 1536; e += 512) {
        int h = e >> 7, c = e & 127;
        float ssum = sbz[h * 128 + c] + sbz[(12 + h) * 128 + c]
                   + sbz[(24 + h) * 128 + c] + sbz[(36 + h) * 128 + c];
        cat[(size_t)i * CATDIM + h * CATH + 48 + c] = ssum;
    }
}

// ---------------- per-head r_scalar + r_pt (+rotate back, norm); attn bf16
__global__ void head_sum_kernel(const ushort* __restrict__ attn_bf, const float* __restrict__ tmp,
                                const float* __restrict__ rot, const float* __restrict__ tran,
                                float* __restrict__ cat)
{
    int i0 = blockIdx.x * 32;
    int h  = blockIdx.y;
    __shared__ float At[32][65];
    __shared__ float Sr[64][44];
    __shared__ float Rp[32][24];
    int tid = threadIdx.x;
    int il = tid & 31, fg = tid >> 5;
    float acc[5] = {0,0,0,0,0};

    for (int jc = 0; jc < NN; jc += 64) {
        {
            int r = tid >> 3, c8 = (tid & 7) * 8;
            const ushort* src = attn_bf + ((size_t)(i0 + r) * HH + h) * NN + jc + c8;
            BFU v; v.q = *(const uint4*)src;
            #pragma unroll
            for (int q = 0; q < 8; q++) At[r][c8 + q] = bf2f(v.u[q]);
        }
        {
            int jr = tid >> 2, d4 = (tid & 3) * 4;
            *(float4*)&Sr[jr][d4] = *(const float4*)&tmp[(size_t)(jc + jr) * TMPW + 384 + h * 16 + d4];
        }
        for (int e = tid; e < 384; e += 256) {
            int jr = e / 6, p4 = (e % 6) * 4;
            *(float4*)&Sr[jr][16 + p4] = *(const float4*)&tmp[(size_t)(jc + jr) * TMPW + 864 + h * 24 + p4];
        }
        __syncthreads();
        #pragma unroll 4
        for (int j = 0; j < 64; j++) {
            float a = At[il][j];
            #pragma unroll
            for (int q = 0; q < 5; q++) acc[q] += a * Sr[j][fg * 5 + q];
        }
        __syncthreads();
    }

    float* cbase = cat + (size_t)(i0 + il) * CATDIM + h * CATH;
    #pragma unroll
    for (int q = 0; q < 5; q++) {
        int f = fg * 5 + q;
        if (f < 16) cbase[f] = acc[q];
        else Rp[il][f - 16] = acc[q];
    }
    __syncthreads();

    {
        int il2 = tid >> 3, p = tid & 7;
        int i = i0 + il2;
        float gx = Rp[il2][p * 3 + 0] - tran[i * 3 + 0];
        float gy = Rp[il2][p * 3 + 1] - tran[i * 3 + 1];
        float gz = Rp[il2][p * 3 + 2] - tran[i * 3 + 2];
        const float* R = rot + i * 9;
        float lx = R[0] * gx + R[3] * gy + R[6] * gz;
        float ly = R[1] * gx + R[4] * gy + R[7] * gz;
        float lz = R[2] * gx + R[5] * gy + R[8] * gz;
        float nrm = sqrtf(lx * lx + ly * ly + lz * lz + 1e-8f);
        float* cp = cat + (size_t)i * CATDIM + h * CATH;
        cp[16 + p * 3 + 0] = lx; cp[16 + p * 3 + 1] = ly; cp[16 + p * 3 + 2] = lz;
        cp[40 + p] = nrm;
    }
}

// ---------------- out GEMM, K-split
__global__ void out_gemm_split_kernel(const float* __restrict__ cat, const float* __restrict__ Wout,
                                      float* __restrict__ part)
{
    int n0 = blockIdx.x * 64;
    int i0 = blockIdx.y * 64;
    int ks = blockIdx.z * KSPL;
    __shared__ float St[32][68];
    __shared__ float Bs[32][68];
    int tid = threadIdx.x;
    int ty = tid >> 4, tx = tid & 15;
    float acc[4][4] = {{0,0,0,0},{0,0,0,0},{0,0,0,0},{0,0,0,0}};

    for (int k0 = 0; k0 < KSPL; k0 += 32) {
        {
            int r = tid >> 2, c8 = (tid & 3) * 8;
            const float* src = cat + (size_t)(i0 + r) * CATDIM + ks + k0 + c8;
            float4 v0 = *(const float4*)src;
            float4 v1 = *(const float4*)(src + 4);
            St[c8+0][r]=v0.x; St[c8+1][r]=v0.y; St[c8+2][r]=v0.z; St[c8+3][r]=v0.w;
            St[c8+4][r]=v1.x; St[c8+5][r]=v1.y; St[c8+6][r]=v1.z; St[c8+7][r]=v1.w;
        }
        {
            int r = tid >> 3, c8 = (tid & 7) * 8;
            const float* src = Wout + (size_t)(ks + k0 + r) * CSD + n0 + c8;
            *(float4*)&Bs[r][c8]     = *(const float4*)src;
            *(float4*)&Bs[r][c8 + 4] = *(const float4*)(src + 4);
        }
        __syncthreads();
        #pragma unroll
        for (int k = 0; k < 32; k++) {
            float4 a = *(const float4*)&St[k][ty * 4];
            float4 b = *(const float4*)&Bs[k][tx * 4];
            float av[4] = {a.x, a.y, a.z, a.w};
            float bv[4] = {b.x, b.y, b.z, b.w};
            #pragma unroll
            for (int r = 0; r < 4; r++)
                #pragma unroll
                for (int c = 0; c < 4; c++) acc[r][c] += av[r] * bv[c];
        }
        __syncthreads();
    }
    #pragma unroll
    for (int r = 0; r < 4; r++) {
        float4 v = make_float4(acc[r][0], acc[r][1], acc[r][2], acc[r][3]);
        *(float4*)&part[((size_t)blockIdx.z * NN + i0 + ty * 4 + r) * CSD + n0 + tx * 4] = v;
    }
}

__global__ void reduce_out_kernel(const float* __restrict__ part, const float* __restrict__ bout,
                                  float* __restrict__ out)
{
    int v = blockIdx.x * 256 + threadIdx.x;
    int n4 = v % 96;
    float4 o = ((const float4*)bout)[n4];
    const float4* p4 = (const float4*)part;
    #pragma unroll
    for (int s = 0; s < NSPLIT; s++) {
        float4 t = p4[(size_t)s * 49152 + v];
        o.x += t.x; o.y += t.y; o.z += t.z; o.w += t.w;
    }
    ((float4*)out)[v] = o;
}

extern "C" void kernel_launch(void* const* d_in, const int* in_sizes, int n_in,
                              void* d_out, int out_size, void* d_ws, size_t ws_size,
                              hipStream_t stream) {
    const float* s    = (const float*)d_in[0];
    const float* z    = (const float*)d_in[1];
    const float* rot  = (const float*)d_in[2];
    const float* tran = (const float*)d_in[3];
    const float* resm = (const float*)d_in[4];
    const float* Wsq  = (const float*)d_in[5];  const float* bsq = (const float*)d_in[6];
    const float* Wsk  = (const float*)d_in[7];  const float* bsk = (const float*)d_in[8];
    const float* Wsv  = (const float*)d_in[9];  const float* bsv = (const float*)d_in[10];
    const float* Wsb  = (const float*)d_in[11]; const float* bsb = (const float*)d_in[12];
    const float* Wpq  = (const float*)d_in[13]; const float* bpq = (const float*)d_in[14];
    const float* Wpk  = (const float*)d_in[15]; const float* bpk = (const float*)d_in[16];
    const float* Wpv  = (const float*)d_in[17]; const float* bpv = (const float*)d_in[18];
    const float* watt = (const float*)d_in[19]; const float* batt = (const float*)d_in[20];
    const float* tpw  = (const float*)d_in[21];
    const float* Wout = (const float*)d_in[22]; const float* bout = (const float*)d_in[23];
    float* out = (float*)d_out;
    float* ws  = (float*)d_ws;

    float*  tmp     = ws;                        // 589824 floats
    ushort* attn_bf = (ushort*)(ws + 589824);    // 3145728 ushorts (1572864 f-slots)
    float*  cat     = ws + 589824 + 1572864;     // 1081344 floats
    float*  partO   = cat + 1081344;             // 1179648 floats

    proj_gemm_kernel<<<dim3(24, 16), 256, 0, stream>>>(s, rot, tran,
                                                       Wsq, bsq, Wsk, bsk, Wsv, bsv,
                                                       Wpq, bpq, Wpk, bpk, Wpv, bpv, tmp);
    fused_z_kernel<<<512, 512, 0, stream>>>(z, resm, Wsb, bsb, watt, batt, tpw,
                                            tmp, attn_bf, cat);
    head_sum_kernel<<<dim3(16, 12), 256, 0, stream>>>(attn_bf, tmp, rot, tran, cat);
    out_gemm_split_kernel<<<dim3(6, 8, NSPLIT), 256, 0, stream>>>(cat, Wout, partO);
    reduce_out_kernel<<<192, 256, 0, stream>>>(partO, bout, out);
}